// Round 10
// baseline (569.485 us; speedup 1.0000x reference)
//
#include <hip/hip_runtime.h>
#include <hip/hip_bf16.h>

#define BB 4
#define TT 4096
#define HH 2048
#define NHH 16
#define VOC 100000
#define EE 1024
#define GG 4
#define BT (BB*TT)          // 16384 tokens, p = b*TT + t
#define NKEY (GG*HH)        // 8192
#define NTOT (NKEY+HH)      // 10240
#define NPART 32
#define TCV 48              // conv t-chunk (multiple of 3)

static constexpr float EPS_RMS = 1.1920929e-07f;
static constexpr float EPS_SC  = 1e-5f;
static constexpr float INV_SQRT_H = 0.02209708691207961f; // 1/sqrt(2048)

using f32x4 = __attribute__((ext_vector_type(4))) float;
using f32x2 = __attribute__((ext_vector_type(2))) float;
using s8v   = __attribute__((ext_vector_type(8))) short;
using gvoid = __attribute__((address_space(1))) const void;
using lvoid = __attribute__((address_space(3))) void;

__device__ __forceinline__ unsigned short f2bf(float f){
  union { __hip_bfloat16 h; unsigned short u; } cv;
  cv.h = __float2bfloat16(f);
  return cv.u;
}
__device__ __forceinline__ float bf2f(unsigned short u){
  union { float f; unsigned u; } cv;
  cv.u = ((unsigned)u) << 16;
  return cv.f;
}

// ---------------- weight convert: [keyW | valueW] -> bf16 [10240,1024] ----------------
__global__ __launch_bounds__(256) void convw_kern(const float* __restrict__ kW,
    const float* __restrict__ vW, unsigned short* __restrict__ Wc){
  const long idx  = (long)blockIdx.x*256 + threadIdx.x;
  const long base = idx*4;
  const long KN   = (long)NKEY*EE;
  float4 v;
  if (base < KN) v = *(const float4*)(kW + base);
  else           v = *(const float4*)(vW + (base - KN));
  ushort4 o; o.x=f2bf(v.x); o.y=f2bf(v.y); o.z=f2bf(v.z); o.w=f2bf(v.w);
  *(ushort4*)(Wc + base) = o;
}

// ---------------- fused prep: hashed gather -> emb bf16 ; rq[p] ; hsbf [p][h] bf16 ----------------
__global__ __launch_bounds__(256) void prep_kern(const int* __restrict__ hids,
    const float* __restrict__ table, unsigned short* __restrict__ emb,
    const float* __restrict__ hs, float* __restrict__ rq,
    unsigned short* __restrict__ hsbf){
  const int p = blockIdx.x, tid = threadIdx.x;
  const int e = tid*4, head = e>>6, d = e&63;
  const long row = (long)hids[p*NHH + head] + (long)head*VOC;
  const float4 v = *(const float4*)(table + row*64 + d);
  ushort4 o; o.x=f2bf(v.x); o.y=f2bf(v.y); o.z=f2bf(v.z); o.w=f2bf(v.w);
  *(ushort4*)(emb + (size_t)p*EE + e) = o;
  const int b = p>>12, t = p&4095;
  const float* hrow = hs + ((size_t)t*BB + b)*HH;
  const int e8 = tid*8;
  float4 v0 = *(const float4*)(hrow+e8);
  float4 v1 = *(const float4*)(hrow+e8+4);
  ushort4 hb0; hb0.x=f2bf(v0.x); hb0.y=f2bf(v0.y); hb0.z=f2bf(v0.z); hb0.w=f2bf(v0.w);
  ushort4 hb1; hb1.x=f2bf(v1.x); hb1.y=f2bf(v1.y); hb1.z=f2bf(v1.z); hb1.w=f2bf(v1.w);
  *(ushort4*)(hsbf + (size_t)p*HH + e8)     = hb0;
  *(ushort4*)(hsbf + (size_t)p*HH + e8 + 4) = hb1;
  float s = v0.x*v0.x+v0.y*v0.y+v0.z*v0.z+v0.w*v0.w
          + v1.x*v1.x+v1.y*v1.y+v1.z*v1.z+v1.w*v1.w;
  #pragma unroll
  for (int of=32;of>=1;of>>=1) s += __shfl_xor(s,of);
  __shared__ float red[4];
  if ((tid&63)==0) red[tid>>6] = s;
  __syncthreads();
  if (tid==0){
    float tot = red[0]+red[1]+red[2]+red[3];
    rq[p] = rsqrtf(tot*(1.0f/HH) + EPS_RMS);
  }
}

// ======== 256x256 GEMM, BK=32, TRIPLE-buffered LDS (3x32KB), counted vmcnt(4) ========
__global__ __launch_bounds__(512, 2) void gemm8(
    const unsigned short* __restrict__ A, const unsigned short* __restrict__ Bw,
    const float* __restrict__ key_b, const float* __restrict__ value_b,
    const float* __restrict__ n1w, const float* __restrict__ n2w,
    const unsigned short* __restrict__ hsbf, unsigned short* __restrict__ vlinb,
    f32x2* __restrict__ sdp, float* __restrict__ vsqp)
{
  __shared__ char sh[98304];   // 96 KiB: 3 bufs x 32 KiB ([A 16KB | B 16KB], 64 B rows)
  const int tid = threadIdx.x, w = tid>>6, l = tid&63;
  const int wm = w>>2, wn = w&3;
  const int lg = l&15, lr = l>>4;
  // XCD-aware bijective swizzle: 2560 blocks, 8 XCDs, 320/XCD = 8 contiguous tM rows
  const int wg  = blockIdx.x;
  const int swz = (wg&7)*320 + (wg>>3);
  const int tM  = swz/40, tN = swz - tM*40;
  const int Mrow0 = tM*256, Nrow0 = tN*256;

  // Staging (BK=32): each gload_lds covers 16 rows x 64 B; lane l -> row l>>2, chunk l&3.
  // Bank swizzle: LDS (row,chunk) holds global chunk (chunk ^ (row&3));
  // source chunk for lane l: (l&3) ^ ((l>>2)&3). Per-lane source offset (shorts):
  const int srow = l>>2, schunk = (l&3) ^ (srow&3);
  const size_t aoffS = (size_t)(Mrow0 + w*32 + srow)*EE + schunk*8;
  const size_t boffS = (size_t)(Nrow0 + w*32 + srow)*EE + schunk*8;
  // ds_read: row = (wm*128|wn*64) + f*16 + lg; chunk' = lr ^ (row&3) = lr ^ (lg&3)
  const unsigned cSw = (unsigned)((lr ^ (lg&3))<<4);
  const unsigned aB0 = (unsigned)(wm*8192 + lg*64) + cSw;          // + mf*1024
  const unsigned bB0 = 16384u + (unsigned)(wn*4096 + lg*64) + cSw; // + nf*1024

  f32x4 acc[8][4] = {};
  s8v aF0, aF1, aR2, aR3, aR4, aR5, aR6, aR7;
  s8v bP[4], bQ[4];

#define BAR() { asm volatile("" ::: "memory"); __builtin_amdgcn_s_barrier(); asm volatile("" ::: "memory"); }
#define WAITV(N) asm volatile("s_waitcnt vmcnt(" #N ")" ::: "memory")

// one stage load: ISB operand (0=A,1=B), J row-half (0/1), KT k-tile, SB dest buffer
#define STG(ISB, J, KT, SB) { \
    const unsigned short* s_ = ((ISB) ? (Bw + boffS) : (A + aoffS)) + (J)*16*EE + (KT)*32; \
    __builtin_amdgcn_global_load_lds((gvoid*)s_, \
        (lvoid*)(sh + (SB)*32768 + (ISB)*16384 + w*2048 + (J)*1024), 16, 0, 0); }
#define STAGE4(KT, SB) { STG(0,0,KT,SB); STG(0,1,KT,SB); STG(1,0,KT,SB); STG(1,1,KT,SB); }

#define RD_A(CB, MF, DST) { DST = *(const s8v*)(sh + (CB)*32768 + aB0 + (MF)*1024); }
#define RD_B(CB, DSTARR) { \
    DSTARR[0] = *(const s8v*)(sh + (CB)*32768 + bB0 + 0*1024); \
    DSTARR[1] = *(const s8v*)(sh + (CB)*32768 + bB0 + 1*1024); \
    DSTARR[2] = *(const s8v*)(sh + (CB)*32768 + bB0 + 2*1024); \
    DSTARR[3] = *(const s8v*)(sh + (CB)*32768 + bB0 + 3*1024); }

#define MM4(MF, AF, BF) { \
    __builtin_amdgcn_s_setprio(1); \
    acc[MF][0] = __builtin_amdgcn_mfma_f32_16x16x32_bf16(AF, BF[0], acc[MF][0], 0,0,0); \
    acc[MF][1] = __builtin_amdgcn_mfma_f32_16x16x32_bf16(AF, BF[1], acc[MF][1], 0,0,0); \
    acc[MF][2] = __builtin_amdgcn_mfma_f32_16x16x32_bf16(AF, BF[2], acc[MF][2], 0,0,0); \
    acc[MF][3] = __builtin_amdgcn_mfma_f32_16x16x32_bf16(AF, BF[3], acc[MF][3], 0,0,0); \
    __builtin_amdgcn_s_setprio(0); }

// Tile k: CB=k%3 compute; SB=(k+2)%3 stage tile k+2; NB=(k+1)%3 prefetch-read next frags.
// BC = this tile's B regs; BN = next tile's (ping-pong).
#define TILEX(CB, NB, SB, KT2, BC, BN, DOST, WMACRO) { \
    BAR(); \
    if (DOST) STAGE4(KT2, SB); \
    RD_A(CB,2,aR2); RD_A(CB,3,aR3); \
    MM4(0, aF0, BC); \
    RD_A(CB,4,aR4); RD_A(CB,5,aR5); \
    MM4(1, aF1, BC); \
    RD_A(CB,6,aR6); RD_A(CB,7,aR7); \
    MM4(2, aR2, BC); MM4(3, aR3, BC); \
    WMACRO; \
    BAR(); \
    MM4(4, aR4, BC); MM4(5, aR5, BC); \
    RD_A(NB,0,aF0); RD_A(NB,1,aF1); RD_B(NB, BN); \
    MM4(6, aR6, BC); MM4(7, aR7, BC); }

#define TILE_FIN(CB, BC) { \
    BAR(); \
    RD_A(CB,2,aR2); RD_A(CB,3,aR3); \
    MM4(0, aF0, BC); \
    RD_A(CB,4,aR4); RD_A(CB,5,aR5); \
    MM4(1, aF1, BC); \
    RD_A(CB,6,aR6); RD_A(CB,7,aR7); \
    MM4(2, aR2, BC); MM4(3, aR3, BC); MM4(4, aR4, BC); MM4(5, aR5, BC); \
    MM4(6, aR6, BC); MM4(7, aR7, BC); }

  // prologue: stage tiles 0,1 into bufs 0,1; wait tile 0 only; preload tile-0 frags
  STAGE4(0, 0);
  STAGE4(1, 1);
  WAITV(4);
  BAR();
  RD_A(0,0,aF0); RD_A(0,1,aF1); RD_B(0, bP);

  #pragma unroll 1
  for (int i=0; i<5; i++){           // tiles 6i .. 6i+5 (0..29)
    const int k6 = 6*i;
    TILEX(0,1,2, k6+2, bP,bQ, 1, WAITV(4));
    TILEX(1,2,0, k6+3, bQ,bP, 1, WAITV(4));
    TILEX(2,0,1, k6+4, bP,bQ, 1, WAITV(4));
    TILEX(0,1,2, k6+5, bQ,bP, 1, WAITV(4));
    TILEX(1,2,0, k6+6, bP,bQ, 1, WAITV(4));
    TILEX(2,0,1, k6+7, bQ,bP, 1, WAITV(4));
  }
  TILEX(0,1,2, 0, bP,bQ, 0, WAITV(0));   // tile 30: no stage, full drain of tile 31's loads
  TILE_FIN(1, bQ);                        // tile 31

#undef BAR
#undef WAITV
#undef STG
#undef STAGE4
#undef RD_A
#undef RD_B
#undef MM4
#undef TILEX
#undef TILE_FIN

  asm volatile("" ::: "memory"); __builtin_amdgcn_s_barrier(); asm volatile("" ::: "memory");

  // ---- epilogue ----
  const bool isK = (Nrow0 < NKEY);
  float bias[4], cw[4]; int hcol[4];
  #pragma unroll
  for (int nf=0; nf<4; nf++){
    const int n = Nrow0 + wn*64 + nf*16 + lg;
    hcol[nf] = n & (HH-1);
    if (isK){ bias[nf] = key_b[n]; cw[nf] = n1w[n]*n2w[n]; }
    else    { bias[nf] = value_b[n-NKEY]; cw[nf] = 0.f; }
  }

  if (isK){
    const int g = Nrow0 >> 11;
    const int slot = (tN&7)*4 + wn;
    char* wreg = sh + w*8192;   // 8 KB private region per wave, two passes
    #pragma unroll
    for (int half=0; half<2; half++){
      #pragma unroll
      for (int mfs=0; mfs<4; mfs++){
        const int mfa = half*4 + mfs;
        #pragma unroll
        for (int rr=0; rr<4; rr++){
          const int rowl2 = mfs*16 + lr*4 + rr;            // 0..63
          const int p = Mrow0 + wm*128 + half*64 + rowl2;
          const unsigned short* hrow = hsbf + (size_t)p*HH;
          float ssq=0.f, dt=0.f;
          #pragma unroll
          for (int nf=0; nf<4; nf++){
            const float c = acc[mfa][nf][rr] + bias[nf];
            ssq += c*c;
            dt  += c * cw[nf] * bf2f(hrow[hcol[nf]]);
          }
          f32x2 pr; pr[0]=ssq; pr[1]=dt;
          *(f32x2*)(wreg + rowl2*128 + (((lg>>1) ^ (rowl2&7))<<4) + ((lg&1)<<3)) = pr;
        }
      }
      {
        const int r = l;
        float ssq=0.f, dt=0.f;
        #pragma unroll
        for (int c=0; c<8; c++){
          f32x4 v = *(const f32x4*)(wreg + r*128 + ((c ^ (r&7))<<4));
          ssq += v[0] + v[2]; dt += v[1] + v[3];
        }
        const int p = Mrow0 + wm*128 + half*64 + r;
        f32x2 o; o[0]=ssq; o[1]=dt;
        sdp[(size_t)(p*GG+g)*NPART + slot] = o;
      }
    }
  } else {
    const int slot = (tN-32)*4 + wn;
    const int h0 = Nrow0 - NKEY + wn*64;
    const int pbase = Mrow0 + wm*128;
    #pragma unroll
    for (int mfa=0; mfa<8; mfa++){
      #pragma unroll
      for (int rr=0; rr<4; rr++){
        const int p = pbase + mfa*16 + lr*4 + rr;
        float ssq=0.f;
        #pragma unroll
        for (int nf=0; nf<4; nf++){
          const float c = acc[mfa][nf][rr] + bias[nf];
          vlinb[(size_t)p*HH + h0 + nf*16 + lg] = f2bf(c);
          ssq += c*c;
        }
        #pragma unroll
        for (int o=1;o<16;o<<=1){ ssq += __shfl_xor(ssq,o); }
        if (lg==0) vsqp[(size_t)p*NPART + slot] = ssq;
      }
    }
  }
}

// ---------------- per-(token,group) scalars: gate + xn-scale a ----------------
__global__ __launch_bounds__(256) void scal_kern(const f32x2* __restrict__ sdp,
    const float* __restrict__ vsqp,
    const float* __restrict__ rq, float* __restrict__ gate, float* __restrict__ av){
  const int i = blockIdx.x*256 + threadIdx.x;   // BT*GG
  const int p = i>>2;
  float ss=0.f, dd=0.f, vv=0.f;
  const f32x2* sp = sdp + (size_t)i*NPART;
  #pragma unroll
  for (int j=0;j<NPART;j++){ f32x2 v = sp[j]; ss += v[0]; dd += v[1]; }
  #pragma unroll
  for (int j=0;j<NPART;j++){ vv += vsqp[(size_t)p*NPART+j]; }
  const float rk = rsqrtf(ss*(1.0f/HH) + EPS_RMS);
  const float gv = rk * rq[p] * dd * INV_SQRT_H;
  const float sgn = (gv>0.f)?1.f:((gv<0.f)?-1.f:0.f);
  const float g1 = sqrtf(fmaxf(fabsf(gv),1e-6f))*sgn;
  const float gt = 1.f/(1.f+__expf(-g1));
  const float msvl = vv*(1.0f/HH);
  const float a = gt * rsqrtf(gt*gt*msvl + EPS_SC);
  gate[i]=gt; av[i]=a;
}

// ---------------- conv: residue-mod-3 register window (vl and av), weights loaded once ----------------
__device__ __forceinline__ ushort4 ldrow(const unsigned short* __restrict__ v, int b, int t, int h0){
  if (t < 0){ ushort4 z; z.x=0;z.y=0;z.z=0;z.w=0; return z; }
  return *(const ushort4*)(v + (size_t)((b<<12)|t)*HH + h0);
}
__device__ __forceinline__ void ldav(const float* __restrict__ av, int b, int t, float* a){
  if (t < 0){ a[0]=0.f;a[1]=0.f;a[2]=0.f;a[3]=0.f; }
  else { const float4 x = *(const float4*)(av + (size_t)((b<<12)|t)*GG);
         a[0]=x.x;a[1]=x.y;a[2]=x.z;a[3]=x.w; }
}

__global__ __launch_bounds__(256) void conv2_kern(const unsigned short* __restrict__ vlinb,
    const float* __restrict__ gate, const float* __restrict__ av,
    const float* __restrict__ conv_w, const float* __restrict__ scw,
    float* __restrict__ out){
  const int bx = blockIdx.x;
  const int b  = blockIdx.y;
  const int t0 = (bx>>1)*TCV;
  const int h0 = (bx&1)*1024 + threadIdx.x*4;

  float cwv[4][4][4];
  float sc4[4][4];
  #pragma unroll
  for (int g=0; g<4; g++){
    #pragma unroll
    for (int j2=0; j2<4; j2++){
      const int c = g*HH + h0 + j2;
      const float4 wv = *(const float4*)(conv_w + (size_t)c*4);
      cwv[g][j2][0]=wv.x; cwv[g][j2][1]=wv.y; cwv[g][j2][2]=wv.z; cwv[g][j2][3]=wv.w;
      sc4[g][j2] = scw[c];
    }
  }

  #pragma unroll 1
  for (int r=0; r<3; r++){
    const int tf = t0 + r;
    ushort4 w0 = ldrow(vlinb, b, tf-9, h0);
    ushort4 w1 = ldrow(vlinb, b, tf-6, h0);
    ushort4 w2 = ldrow(vlinb, b, tf-3, h0);
    ushort4 w3; w3.x=0;w3.y=0;w3.z=0;w3.w=0;
    float a0[4],a1[4],a2[4],a3[4];
    ldav(av, b, tf-9, a0); ldav(av, b, tf-6, a1); ldav(av, b, tf-3, a2);
    #pragma unroll
    for (int j=0; j<16; j++){
      const int t = tf + 3*j;
      if (t < TT){
        const int p = (b<<12)|t;
        w3 = *(const ushort4*)(vlinb + (size_t)p*HH + h0);
        ldav(av, b, t, a3);
        float gt4[4];
        { const float4 xx = *(const float4*)(gate + (size_t)p*GG);
          gt4[0]=xx.x; gt4[1]=xx.y; gt4[2]=xx.z; gt4[3]=xx.w; }
        float v0[4],v1[4],v2[4],v3[4];
        v0[0]=bf2f(w0.x); v0[1]=bf2f(w0.y); v0[2]=bf2f(w0.z); v0[3]=bf2f(w0.w);
        v1[0]=bf2f(w1.x); v1[1]=bf2f(w1.y); v1[2]=bf2f(w1.z); v1[3]=bf2f(w1.w);
        v2[0]=bf2f(w2.x); v2[1]=bf2f(w2.y); v2[2]=bf2f(w2.z); v2[3]=bf2f(w2.w);
        v3[0]=bf2f(w3.x); v3[1]=bf2f(w3.y); v3[2]=bf2f(w3.z); v3[3]=bf2f(w3.w);
        float4 ov;
        float res[4];
        #pragma unroll
        for (int j2=0; j2<4; j2++){
          float acc = 0.f;
          #pragma unroll
          for (int g=0; g<4; g++){
            float y = cwv[g][j2][0]*a0[g]*v0[j2]
                    + cwv[g][j2][1]*a1[g]*v1[j2]
                    + cwv[g][j2][2]*a2[g]*v2[j2]
                    + cwv[g][j2][3]*a3[g]*v3[j2];
            y *= sc4[g][j2];
            const float sy = y * (1.f/(1.f+__expf(-y)));
            acc += gt4[g]*v3[j2] + sy;
          }
          res[j2] = acc*0.25f;
        }
        ov.x=res[0]; ov.y=res[1]; ov.z=res[2]; ov.w=res[3];
        *(float4*)(out + ((size_t)t*BB + b)*HH + h0) = ov;
      }
      w0=w1; w1=w2; w2=w3;
      #pragma unroll
      for (int g=0; g<4; g++){ a0[g]=a1[g]; a1[g]=a2[g]; a2[g]=a3[g]; }
    }
  }
}

extern "C" void kernel_launch(void* const* d_in, const int* in_sizes, int n_in,
                              void* d_out, int out_size, void* d_ws, size_t ws_size,
                              hipStream_t stream){
  (void)in_sizes; (void)n_in; (void)out_size; (void)ws_size;
  const float* hs    = (const float*)d_in[0];
  const int*   hids  = (const int*)d_in[1];
  const float* table = (const float*)d_in[2];
  const float* keyW  = (const float*)d_in[3];
  const float* keyB  = (const float*)d_in[4];
  const float* valW  = (const float*)d_in[5];
  const float* valB  = (const float*)d_in[6];
  const float* n1w   = (const float*)d_in[7];
  const float* n2w   = (const float*)d_in[8];
  const float* scw   = (const float*)d_in[9];
  const float* convw = (const float*)d_in[10];
  float* out = (float*)d_out;

  char* ws = (char*)d_ws;
  size_t off = 0;
  unsigned short* emb   = (unsigned short*)(ws+off); off += (size_t)BT*EE*2;      // 33.5 MB
  unsigned short* Wc    = (unsigned short*)(ws+off); off += (size_t)NTOT*EE*2;    // 21 MB
  unsigned short* vlinb = (unsigned short*)(ws+off); off += (size_t)BT*HH*2;      // 67 MB
  unsigned short* hsbf  = (unsigned short*)(ws+off); off += (size_t)BT*HH*2;      // 67 MB
  f32x2* sdp    = (f32x2*)(ws+off); off += (size_t)BT*GG*NPART*8;                 // 16.8 MB
  float* vsqp   = (float*)(ws+off); off += (size_t)BT*NPART*4;                    // 2.1 MB
  float* rq     = (float*)(ws+off); off += (size_t)BT*4;
  float* gate   = (float*)(ws+off); off += (size_t)BT*GG*4;
  float* av     = (float*)(ws+off); off += (size_t)BT*GG*4;

  convw_kern<<<(NTOT*EE/4)/256, 256, 0, stream>>>(keyW, valW, Wc);
  prep_kern<<<BT, 256, 0, stream>>>(hids, table, emb, hs, rq, hsbf);
  gemm8<<<2560, 512, 0, stream>>>(emb, Wc, keyB, valB, n1w, n2w, hsbf, vlinb, sdp, vsqp);
  scal_kern<<<(BT*GG)/256, 256, 0, stream>>>(sdp, vsqp, rq, gate, av);
  dim3 cg(((TT + TCV - 1)/TCV)*2, BB);  // 172 x 4
  conv2_kern<<<cg, 256, 0, stream>>>(vlinb, gate, av, convw, scw, out);
}